// Round 12
// baseline (106.947 us; speedup 1.0000x reference)
//
#include <hip/hip_runtime.h>

#define PI_F 3.141592653f
#define NB 1024
#define NW 16            // 16 x u64 words per 1024-bit row
#define IOU_THR_F 0.1f
#define NBLK 256
#define MB_MAGIC 0x33333333u

__device__ __forceinline__ float limit_period_f(float v) {
    return v - floorf(v / (2.0f * PI_F) + 0.5f) * (2.0f * PI_F);
}

// swizzled word index: word w of row r lives at r*16 + (w ^ (r&15))
__device__ __forceinline__ int widx(int r, int w) {
    return (r << 4) | (w ^ (r & 15));
}

// Exact rotated-BEV 3D IoU, bit-identical to reference iou3d_pair(boxes[i], boxes[j]):
// A = boxes[i] rect clipped by B = boxes[j] edges. vxs/vys: [2][8][256] LDS scratch.
__device__ __forceinline__ float iou_pair(const float* __restrict__ boxes, int i, int j,
                                          float* vxs, float* vys, int tid)
{
    const float xi  = boxes[i*7+0], yi  = boxes[i*7+1], zi  = boxes[i*7+2];
    const float dxi = boxes[i*7+3], dyi = boxes[i*7+4], dzi = boxes[i*7+5];
    const float aang = limit_period_f(boxes[i*7+6]);
    const float xj  = boxes[j*7+0], yj  = boxes[j*7+1], zj  = boxes[j*7+2];
    const float dxj = boxes[j*7+3], dyj = boxes[j*7+4], dzj = boxes[j*7+5];
    const float bang = limit_period_f(boxes[j*7+6]);

    float ca, sa, cb, sb;
    sincosf(aang, &sa, &ca);
    sincosf(bang, &sb, &cb);

    {
        const float hx = 0.5f*dxi, hy = 0.5f*dyi;
        const float lxs[4] = { hx, -hx, -hx, hx };
        const float lys[4] = { hy, hy, -hy, -hy };
        #pragma unroll
        for (int k = 0; k < 4; ++k) {
            vxs[(0*8+k)*256 + tid] = lxs[k]*ca - lys[k]*sa + xi;
            vys[(0*8+k)*256 + tid] = lxs[k]*sa + lys[k]*ca + yi;
        }
    }
    float pbx[4], pby[4];
    {
        const float hx = 0.5f*dxj, hy = 0.5f*dyj;
        const float lxs[4] = { hx, -hx, -hx, hx };
        const float lys[4] = { hy, hy, -hy, -hy };
        #pragma unroll
        for (int k = 0; k < 4; ++k) {
            pbx[k] = lxs[k]*cb - lys[k]*sb + xj;
            pby[k] = lxs[k]*sb + lys[k]*cb + yj;
        }
    }

    int n = 4;
    int cur = 0;
    #pragma unroll
    for (int e4 = 0; e4 < 4; ++e4) {
        const float eax = pbx[e4], eay = pby[e4];
        const float ebx2 = pbx[(e4+1)&3], eby2 = pby[(e4+1)&3];
        const float dx = ebx2 - eax, dy = eby2 - eay;
        int m = 0;
        if (n > 0) {
            int pidx = n - 1; if (pidx > 7) pidx = 7;
            float px = vxs[(cur*8+pidx)*256 + tid];
            float py = vys[(cur*8+pidx)*256 + tid];
            float sq = dx*(py - eay) - dy*(px - eax);
            #pragma unroll
            for (int k = 0; k < 8; ++k) {
                if (k < n) {
                    const float cx = vxs[(cur*8+k)*256 + tid];
                    const float cy = vys[(cur*8+k)*256 + tid];
                    const float sp = dx*(cy - eay) - dy*(cx - eax);
                    const bool in_p = (sp >= 0.0f);
                    const bool in_q = (sq >= 0.0f);
                    if (in_p != in_q) {
                        float den = sq - sp;
                        den = (fabsf(den) < 1e-9f) ? 1e-9f : den;   // ref semantics
                        const float t = sq / den;
                        if (m < 8) {
                            vxs[((cur^1)*8+m)*256 + tid] = px + t*(cx - px);
                            vys[((cur^1)*8+m)*256 + tid] = py + t*(cy - py);
                        }
                        ++m;
                    }
                    if (in_p) {
                        if (m < 8) {
                            vxs[((cur^1)*8+m)*256 + tid] = cx;
                            vys[((cur^1)*8+m)*256 + tid] = cy;
                        }
                        ++m;
                    }
                    px = cx; py = cy; sq = sp;
                }
            }
        }
        n = m;
        cur ^= 1;
    }

    float area = 0.0f;
    if (n >= 3) {
        float s = 0.0f;
        const float x0 = vxs[(cur*8+0)*256 + tid];
        const float y0 = vys[(cur*8+0)*256 + tid];
        #pragma unroll
        for (int k = 0; k < 8; ++k) {
            if (k < n) {
                float nx, ny;
                if (k == n - 1) { nx = x0; ny = y0; }
                else {
                    int nk = k + 1; if (nk > 7) nk = 7;
                    nx = vxs[(cur*8+nk)*256 + tid]; ny = vys[(cur*8+nk)*256 + tid];
                }
                s += vxs[(cur*8+k)*256 + tid]*ny - vys[(cur*8+k)*256 + tid]*nx;
            }
        }
        area = 0.5f * fabsf(s);
    }

    const float zh = fminf(zi + dzi*0.5f, zj + dzj*0.5f);
    const float zl = fmaxf(zi - dzi*0.5f, zj - dzj*0.5f);
    const float h = fmaxf(zh - zl, 0.0f);
    const float inter = area * h;
    const float va = dxi*dyi*dzi;
    const float vb = dxj*dyj*dzj;
    return inter / fmaxf(va + vb - inter, 1e-6f);
}

// ---------------------------------------------------------------------------
// Single persistent kernel, 256 blocks x 256 threads, 1 block/CU (~134KB LDS).
// ONE sync stage (slot publish/poll); every block then stages the full bit
// matrix and computes the clustering REDUNDANTLY (CUs would otherwise idle),
// eliminating the block-0 serial section and the second broadcast entirely.
// ---------------------------------------------------------------------------
__global__ __launch_bounds__(256) void fused_kernel(
    const float* __restrict__ boxes,
    const float* __restrict__ scores,
    float* __restrict__ out,
    unsigned long long* __restrict__ maskT,
    unsigned int* __restrict__ slotB)
{
    extern __shared__ char smem[];
    __shared__ int candN;
    const int tid = threadIdx.x;
    const int b = blockIdx.x;
    const int lane = tid & 63;
    const int wave = tid >> 6;

    float* vxs = (float*)smem;                                           // 16 KB
    float* vys = (float*)(smem + 16384);                                 // 16 KB
    unsigned long long (*rowW)[NW] = (unsigned long long (*)[NW])(smem + 32768); // 512 B
    unsigned int* candL = (unsigned int*)(smem + 33280);                 // 16 KB (cap 4096)

    if (tid == 0) candN = 0;
    __syncthreads();

    // ---- phase 1a: conservative prefilter for my 4 rows ----
    // d > rA+rB => rects disjoint => iou=0; (ra+rb)^2 <= 2(ra2+rb2) (AM-GM).
    for (int rr = 0; rr < 4; ++rr) {
        const int j = b * 4 + rr;
        const float xj  = boxes[j*7+0], yj  = boxes[j*7+1];
        const float dxj = boxes[j*7+3], dyj = boxes[j*7+4];
        const float rb2 = 0.25f*(dxj*dxj + dyj*dyj);
        #pragma unroll
        for (int q = 0; q < 4; ++q) {
            const int i = q*256 + tid;
            const float xi  = boxes[i*7+0], yi  = boxes[i*7+1];
            const float dxi = boxes[i*7+3], dyi = boxes[i*7+4];
            const float ddx = xi - xj, ddy = yi - yj;
            const float d2 = ddx*ddx + ddy*ddy;
            const float ra2 = 0.25f*(dxi*dxi + dyi*dyi);
            const bool cand = d2 <= 2.0f*(ra2 + rb2);

            const unsigned long long bal = __ballot(cand);
            const int w = q*4 + wave;
            if (lane == 0) rowW[rr][w] = bal;          // superset; 1b clears in LDS

            unsigned long long keep = bal;
            if ((j >> 6) == w) keep &= ~(1ull << (j & 63));   // diag: always true
            int basep = 0;
            if (lane == 0 && keep) basep = atomicAdd(&candN, (int)__popcll(keep));
            basep = __shfl(basep, 0);
            if ((keep >> lane) & 1ull) {
                const int pos = basep + (int)__popcll(keep & ((1ull << lane) - 1ull));
                candL[pos] = ((unsigned)rr << 10) | (unsigned)i;
            }
        }
    }
    __syncthreads();
    const int nc = candN;

    // ---- phase 1b: exact clips for my candidates; clear false bits in LDS ----
    for (int e = tid; e < nc; e += 256) {
        const unsigned int ent = candL[e];
        const int rr = (int)(ent >> 10);
        const int i  = (int)(ent & 1023u);
        const int j  = b * 4 + rr;
        const float iou = iou_pair(boxes, i, j, vxs, vys, tid);
        if (!(iou > IOU_THR_F)) {
            unsigned int* hw = (unsigned int*)&rowW[rr][i >> 6];
            atomicAnd(&hw[(i >> 5) & 1], ~(1u << (i & 31)));   // LDS 32-bit atomic
        }
    }
    __syncthreads();

    // ---- publish all 64 words (wave 0, coalesced: idx b*64+tid) ----
    if (tid < 64) {
        __hip_atomic_store(&maskT[(size_t)b*64 + tid], rowW[tid >> 4][tid & 15],
                           __ATOMIC_RELAXED, __HIP_MEMORY_SCOPE_AGENT);
    }
    __syncthreads();   // phase-1 LDS dead from here
    if (tid == 0) {
        asm volatile("s_waitcnt vmcnt(0)" ::: "memory");   // wave-0 stores at CP
        __hip_atomic_store(&slotB[b * 32], MB_MAGIC,
                           __ATOMIC_RELAXED, __HIP_MEMORY_SCOPE_AGENT);
    }

    // ---- single sync stage: thread t waits for publisher block t ----
    while (__hip_atomic_load(&slotB[tid * 32], __ATOMIC_RELAXED,
                             __HIP_MEMORY_SCOPE_AGENT) != MB_MAGIC)
        __builtin_amdgcn_s_sleep(2);
    __syncthreads();

    // ---- stage FULL matrix locally (coalesced, full MLP) ----
    unsigned long long* mat = (unsigned long long*)smem;                 // 128 KB
    unsigned long long* seed_lds = (unsigned long long*)(smem + 133120); // 16 u64
    int* rankb_lds = (int*)(smem + 133248);                              // 16 int
    int* ci_lds = (int*)(smem + 133312);                                 // 4 KB

    #pragma unroll 8
    for (int it = 0; it < 64; ++it) {
        const int idx = it * 256 + tid;
        const unsigned long long v =
            __hip_atomic_load(&maskT[idx], __ATOMIC_RELAXED, __HIP_MEMORY_SCOPE_AGENT);
        mat[widx(idx >> 4, idx & 15)] = v;
    }
    __syncthreads();

    // ---- cluster phase B (wave 0; seed/rank in wave-uniform registers) ----
    if (tid < 64) {
        unsigned long long seed[NW];
        int rkb[NW];
        #pragma unroll
        for (int w = 0; w < NW; ++w) { seed[w] = 0ull; rkb[w] = 0; }
        int base = 0;

        #pragma unroll
        for (int c = 0; c < NW; ++c) {
            const int row = c * 64 + tid;
            unsigned long long acc = 0ull, Dt = 0ull;
            #pragma unroll
            for (int w = 0; w < NW; ++w) {
                const unsigned long long v = mat[widx(row, w)];
                if (w == c) Dt = v;                  // in-edges within my chunk
                else if (w < c) acc |= v & seed[w];  // future chunks have seed 0
            }
            const bool elig = (acc == 0ull);
            const unsigned long long E = __ballot(elig);
            const unsigned long long inlow = Dt & ((1ull << tid) - 1ull);

            // ballot fixpoint: S(j) = E(j) && no seed t<j with edge t->j
            unsigned long long S = E;
            #pragma unroll 1
            for (int it = 0; it < 64; ++it) {
                const bool killed = (inlow & S) != 0ull;
                const unsigned long long S2 = E & __ballot(!killed);
                if (S2 == S) break;
                S = S2;
            }
            seed[c] = S;
            rkb[c] = base;
            base += (int)__popcll(S);
        }
        if (tid == 0) {
            #pragma unroll
            for (int w = 0; w < NW; ++w) { seed_lds[w] = seed[w]; rankb_lds[w] = rkb[w]; }
        }
    }
    __syncthreads();

    // ---- phase C: label(j) = rank of max-index seed covering j ----
    #pragma unroll
    for (int rr4 = 0; rr4 < 4; ++rr4) {
        const int r = tid * 4 + rr4;
        int best = -1;
        #pragma unroll
        for (int w = 0; w < NW; ++w) {
            const unsigned long long bits = mat[widx(r, w)] & seed_lds[w];
            if (bits) best = (w << 6) | (63 - __clzll(bits));   // w ascending
        }
        int lbl = 0;
        if (best >= 0) {
            const int w = best >> 6, pos = best & 63;
            lbl = rankb_lds[w] + (int)__popcll(seed_lds[w] & ((1ull << pos) - 1ull)) + 1;
        }
        ci_lds[r] = lbl;
    }
    __syncthreads();   // mat dead from here; ms/mi reuse its LDS

    // ---- phase 3: fusion, wave w of block b handles cluster b*4+w+1 ----
    {
        float* ms = (float*)smem + wave * 1024;             // 16 KB total
        int*   mi = (int*)(smem + 16384) + wave * 1024;     // 16 KB total
        const int target = b * 4 + wave + 1;
        const int ob = target - 1;

        unsigned int mymask = 0;
        #pragma unroll
        for (int k = 0; k < 16; ++k) {
            if (ci_lds[lane * 16 + k] == target) mymask |= 1u << k;
        }
        const bool anyv = (__ballot(mymask != 0) != 0ULL);

        float* outb = out + (size_t)ob * 7;
        float* outs = out + 7 * NB;
        float* outv = out + 8 * NB;

        if (!anyv) {
            if (lane == 0) {
                #pragma unroll
                for (int c = 0; c < 7; ++c) outb[c] = 0.0f;
                outs[ob] = 0.0f;
                outv[ob] = 0.0f;
            }
        } else {
            // pass 1: ssum + argmax (first index of max)
            float ssum = 0.0f, smax = -1.0f;
            int sidx = 1 << 30;
            #pragma unroll
            for (int k = 0; k < 16; ++k) {
                if (mymask & (1u << k)) {
                    const int idx = lane * 16 + k;
                    const float s = scores[idx];
                    ssum += s;
                    if (s > smax || (s == smax && idx < sidx)) { smax = s; sidx = idx; }
                }
            }
            #pragma unroll
            for (int off = 32; off >= 1; off >>= 1) {
                ssum += __shfl_xor(ssum, off);
                const float om = __shfl_xor(smax, off);
                const int   oi = __shfl_xor(sidx, off);
                if (om > smax || (om == smax && oi < sidx)) { smax = om; sidx = oi; }
            }
            const float ref = limit_period_f(boxes[sidx * 7 + 6]);

            // pass 2: sc_gt
            float sc_gt = 0.0f;
            #pragma unroll
            for (int k = 0; k < 16; ++k) {
                if (mymask & (1u << k)) {
                    const int idx = lane * 16 + k;
                    const float dir = limit_period_f(boxes[idx * 7 + 6]);
                    float diff = fabsf(dir - ref);
                    if (diff > PI_F) diff = 2.0f * PI_F - diff;
                    if (diff > PI_F * 0.5f) sc_gt += scores[idx];
                }
            }
            #pragma unroll
            for (int off = 32; off >= 1; off >>= 1) sc_gt += __shfl_xor(sc_gt, off);
            const bool flip_gt = (sc_gt <= (ssum - sc_gt));

            // pass 3: weighted sums
            float acc[6] = {0,0,0,0,0,0};
            float ssin = 0.0f, scos = 0.0f;
            #pragma unroll
            for (int k = 0; k < 16; ++k) {
                if (mymask & (1u << k)) {
                    const int idx = lane * 16 + k;
                    const float s = scores[idx];
                    const float w = s / ssum;
                    const float dir = limit_period_f(boxes[idx * 7 + 6]);
                    float diff = fabsf(dir - ref);
                    if (diff > PI_F) diff = 2.0f * PI_F - diff;
                    const bool gt = (diff > PI_F * 0.5f);
                    const bool add = flip_gt ? gt : (!gt);
                    const float d2 = limit_period_f(dir + (add ? PI_F : 0.0f));
                    float sd, cd;
                    sincosf(d2, &sd, &cd);
                    ssin += sd * w;
                    scos += cd * w;
                    #pragma unroll
                    for (int c = 0; c < 6; ++c) acc[c] += boxes[idx * 7 + c] * w;
                }
            }
            #pragma unroll
            for (int off = 32; off >= 1; off >>= 1) {
                ssin += __shfl_xor(ssin, off);
                scos += __shfl_xor(scos, off);
                #pragma unroll
                for (int c = 0; c < 6; ++c) acc[c] += __shfl_xor(acc[c], off);
            }
            const float theta = atan2f(ssin, scos);

            // pass 4: score fusion via tie-broken ranks (== sorted-power sum)
            const int cnt = __popc(mymask);
            int x = cnt;
            #pragma unroll
            for (int off = 1; off < 64; off <<= 1) {
                const int y = __shfl_up(x, off);
                if (lane >= off) x += y;
            }
            const int base = x - cnt;
            const int K = __shfl(x, 63);
            {
                int p = base;
                #pragma unroll
                for (int k = 0; k < 16; ++k) {
                    if (mymask & (1u << k)) {
                        const int idx = lane * 16 + k;
                        ms[p] = scores[idx];
                        mi[p] = idx;
                        ++p;
                    }
                }
            }
            // per-wave buffers: no cross-wave sync needed
            float sf = 0.0f;
            for (int e = lane; e < K; e += 64) {
                const float v = ms[e];
                const int ix = mi[e];
                int rank = 0;
                for (int t = 0; t < K; ++t) {
                    const float u = ms[t];
                    if (u > v || (u == v && mi[t] < ix)) ++rank;
                }
                sf += powf(v, (float)(rank + 1));
            }
            #pragma unroll
            for (int off = 32; off >= 1; off >>= 1) sf += __shfl_xor(sf, off);
            sf = fminf(sf, 1.0f);

            if (lane == 0) {
                #pragma unroll
                for (int c = 0; c < 6; ++c) outb[c] = acc[c];
                outb[6] = theta;
                outs[ob] = sf;
                outv[ob] = 1.0f;
            }
        }
    }
}

// ---------------------------------------------------------------------------
extern "C" void kernel_launch(void* const* d_in, const int* in_sizes, int n_in,
                              void* d_out, int out_size, void* d_ws, size_t ws_size,
                              hipStream_t stream) {
    const float* boxes  = (const float*)d_in[0];   // (1024,7) f32
    const float* scores = (const float*)d_in[1];   // (1024,)  f32
    float* out = (float*)d_out;

    char* ws = (char*)d_ws;
    unsigned long long* maskT = (unsigned long long*)ws;     // 128 KB @ 0
    unsigned int* slotB = (unsigned int*)(ws + 131072);      // 256 slots x 128 B = 32 KB

    const size_t SMEM = 137408;  // max(phase1 ~49K, mat 128K + seed/rank/ci 6.3K, fuse 32K+ci)
    (void)hipFuncSetAttribute((const void*)fused_kernel,
                              hipFuncAttributeMaxDynamicSharedMemorySize, (int)SMEM);
    fused_kernel<<<NBLK, 256, SMEM, stream>>>(boxes, scores, out, maskT, slotB);
}

// Round 13
// 85.073 us; speedup vs baseline: 1.2571x; 1.2571x over previous
//
#include <hip/hip_runtime.h>

#define PI_F 3.141592653f
#define NB 1024
#define NW 16            // 16 x u64 words per 1024-bit row
#define IOU_THR_F 0.1f
#define NBLK 256
#define MB_MAGIC 0x33333333u
#define MC_MAGIC 0x5EEDF00Du

__device__ __forceinline__ float limit_period_f(float v) {
    return v - floorf(v / (2.0f * PI_F) + 0.5f) * (2.0f * PI_F);
}

// swizzled word index: word w of row r lives at r*16 + (w ^ (r&15))
__device__ __forceinline__ int widx(int r, int w) {
    return (r << 4) | (w ^ (r & 15));
}

// Exact rotated-BEV 3D IoU, bit-identical to reference iou3d_pair(boxes[i], boxes[j]):
// A = boxes[i] rect clipped by B = boxes[j] edges. vxs/vys: [2][8][256] LDS scratch.
__device__ __forceinline__ float iou_pair(const float* __restrict__ boxes, int i, int j,
                                          float* vxs, float* vys, int tid)
{
    const float xi  = boxes[i*7+0], yi  = boxes[i*7+1], zi  = boxes[i*7+2];
    const float dxi = boxes[i*7+3], dyi = boxes[i*7+4], dzi = boxes[i*7+5];
    const float aang = limit_period_f(boxes[i*7+6]);
    const float xj  = boxes[j*7+0], yj  = boxes[j*7+1], zj  = boxes[j*7+2];
    const float dxj = boxes[j*7+3], dyj = boxes[j*7+4], dzj = boxes[j*7+5];
    const float bang = limit_period_f(boxes[j*7+6]);

    float ca, sa, cb, sb;
    sincosf(aang, &sa, &ca);
    sincosf(bang, &sb, &cb);

    {
        const float hx = 0.5f*dxi, hy = 0.5f*dyi;
        const float lxs[4] = { hx, -hx, -hx, hx };
        const float lys[4] = { hy, hy, -hy, -hy };
        #pragma unroll
        for (int k = 0; k < 4; ++k) {
            vxs[(0*8+k)*256 + tid] = lxs[k]*ca - lys[k]*sa + xi;
            vys[(0*8+k)*256 + tid] = lxs[k]*sa + lys[k]*ca + yi;
        }
    }
    float pbx[4], pby[4];
    {
        const float hx = 0.5f*dxj, hy = 0.5f*dyj;
        const float lxs[4] = { hx, -hx, -hx, hx };
        const float lys[4] = { hy, hy, -hy, -hy };
        #pragma unroll
        for (int k = 0; k < 4; ++k) {
            pbx[k] = lxs[k]*cb - lys[k]*sb + xj;
            pby[k] = lxs[k]*sb + lys[k]*cb + yj;
        }
    }

    int n = 4;
    int cur = 0;
    #pragma unroll
    for (int e4 = 0; e4 < 4; ++e4) {
        const float eax = pbx[e4], eay = pby[e4];
        const float ebx2 = pbx[(e4+1)&3], eby2 = pby[(e4+1)&3];
        const float dx = ebx2 - eax, dy = eby2 - eay;
        int m = 0;
        if (n > 0) {
            int pidx = n - 1; if (pidx > 7) pidx = 7;
            float px = vxs[(cur*8+pidx)*256 + tid];
            float py = vys[(cur*8+pidx)*256 + tid];
            float sq = dx*(py - eay) - dy*(px - eax);
            #pragma unroll
            for (int k = 0; k < 8; ++k) {
                if (k < n) {
                    const float cx = vxs[(cur*8+k)*256 + tid];
                    const float cy = vys[(cur*8+k)*256 + tid];
                    const float sp = dx*(cy - eay) - dy*(cx - eax);
                    const bool in_p = (sp >= 0.0f);
                    const bool in_q = (sq >= 0.0f);
                    if (in_p != in_q) {
                        float den = sq - sp;
                        den = (fabsf(den) < 1e-9f) ? 1e-9f : den;   // ref semantics
                        const float t = sq / den;
                        if (m < 8) {
                            vxs[((cur^1)*8+m)*256 + tid] = px + t*(cx - px);
                            vys[((cur^1)*8+m)*256 + tid] = py + t*(cy - py);
                        }
                        ++m;
                    }
                    if (in_p) {
                        if (m < 8) {
                            vxs[((cur^1)*8+m)*256 + tid] = cx;
                            vys[((cur^1)*8+m)*256 + tid] = cy;
                        }
                        ++m;
                    }
                    px = cx; py = cy; sq = sp;
                }
            }
        }
        n = m;
        cur ^= 1;
    }

    float area = 0.0f;
    if (n >= 3) {
        float s = 0.0f;
        const float x0 = vxs[(cur*8+0)*256 + tid];
        const float y0 = vys[(cur*8+0)*256 + tid];
        #pragma unroll
        for (int k = 0; k < 8; ++k) {
            if (k < n) {
                float nx, ny;
                if (k == n - 1) { nx = x0; ny = y0; }
                else {
                    int nk = k + 1; if (nk > 7) nk = 7;
                    nx = vxs[(cur*8+nk)*256 + tid]; ny = vys[(cur*8+nk)*256 + tid];
                }
                s += vxs[(cur*8+k)*256 + tid]*ny - vys[(cur*8+k)*256 + tid]*nx;
            }
        }
        area = 0.5f * fabsf(s);
    }

    const float zh = fminf(zi + dzi*0.5f, zj + dzj*0.5f);
    const float zl = fmaxf(zi - dzi*0.5f, zj - dzj*0.5f);
    const float h = fmaxf(zh - zl, 0.0f);
    const float inter = area * h;
    const float va = dxi*dyi*dzi;
    const float vb = dxj*dyj*dzj;
    return inter / fmaxf(va + vb - inter, 1e-6f);
}

// ---------------------------------------------------------------------------
// Single persistent kernel, 256 blocks x 256 threads, 1 block/CU (~135KB LDS).
// Fence-free cross-block sync: data moves via agent-scope relaxed atomics
// (device-coherent point, no L2-writeback fences); ordering data->flag by
// wave-local s_waitcnt vmcnt(0) (all data stores issued by wave 0).
// Block-0-only sparse staging; single flagC broadcast. (R10 best-known-good.)
// ---------------------------------------------------------------------------
__global__ __launch_bounds__(256) void fused_kernel(
    const float* __restrict__ boxes,
    const float* __restrict__ scores,
    float* __restrict__ out,
    unsigned long long* __restrict__ maskT,
    unsigned int* __restrict__ wm_g,
    unsigned long long* __restrict__ ci_pack,
    unsigned int* __restrict__ slotB,
    unsigned int* __restrict__ flagC)
{
    extern __shared__ char smem[];
    __shared__ int candN;
    const int tid = threadIdx.x;
    const int b = blockIdx.x;
    const int lane = tid & 63;
    const int wave = tid >> 6;

    float* vxs = (float*)smem;                                           // 16 KB
    float* vys = (float*)(smem + 16384);                                 // 16 KB
    unsigned long long (*rowW)[NW] = (unsigned long long (*)[NW])(smem + 32768); // 512 B
    unsigned int* candL = (unsigned int*)(smem + 33280);                 // 16 KB (cap 4096)

    if (tid == 0) candN = 0;
    __syncthreads();

    // ---- phase 1a: conservative prefilter for my 4 rows ----
    // d > rA+rB => rects disjoint => iou=0; (ra+rb)^2 <= 2(ra2+rb2) (AM-GM).
    for (int rr = 0; rr < 4; ++rr) {
        const int j = b * 4 + rr;
        const float xj  = boxes[j*7+0], yj  = boxes[j*7+1];
        const float dxj = boxes[j*7+3], dyj = boxes[j*7+4];
        const float rb2 = 0.25f*(dxj*dxj + dyj*dyj);
        #pragma unroll
        for (int q = 0; q < 4; ++q) {
            const int i = q*256 + tid;
            const float xi  = boxes[i*7+0], yi  = boxes[i*7+1];
            const float dxi = boxes[i*7+3], dyi = boxes[i*7+4];
            const float ddx = xi - xj, ddy = yi - yj;
            const float d2 = ddx*ddx + ddy*ddy;
            const float ra2 = 0.25f*(dxi*dxi + dyi*dyi);
            const bool cand = d2 <= 2.0f*(ra2 + rb2);

            const unsigned long long bal = __ballot(cand);
            const int w = q*4 + wave;
            if (lane == 0) rowW[rr][w] = bal;          // superset; 1b clears in LDS

            unsigned long long keep = bal;
            if ((j >> 6) == w) keep &= ~(1ull << (j & 63));   // diag: always true
            int basep = 0;
            if (lane == 0 && keep) basep = atomicAdd(&candN, (int)__popcll(keep));
            basep = __shfl(basep, 0);
            if ((keep >> lane) & 1ull) {
                const int pos = basep + (int)__popcll(keep & ((1ull << lane) - 1ull));
                candL[pos] = ((unsigned)rr << 10) | (unsigned)i;
            }
        }
    }
    __syncthreads();
    const int nc = candN;

    // ---- phase 1b: exact clips for my candidates; clear false bits in LDS ----
    for (int e = tid; e < nc; e += 256) {
        const unsigned int ent = candL[e];
        const int rr = (int)(ent >> 10);
        const int i  = (int)(ent & 1023u);
        const int j  = b * 4 + rr;
        const float iou = iou_pair(boxes, i, j, vxs, vys, tid);
        if (!(iou > IOU_THR_F)) {
            unsigned int* hw = (unsigned int*)&rowW[rr][i >> 6];
            atomicAnd(&hw[(i >> 5) & 1], ~(1u << (i & 31)));   // LDS 32-bit atomic
        }
    }
    __syncthreads();

    // ---- publish final words: wave 0 only (so tid0's vmcnt covers them) ----
    if (tid < 64) {
        const int rr = tid >> 4, w = tid & 15;
        const unsigned long long v = rowW[rr][w];
        const int j = b * 4 + rr;
        if (v != 0ull)
            __hip_atomic_store(&maskT[(size_t)j*NW + w], v,
                               __ATOMIC_RELAXED, __HIP_MEMORY_SCOPE_AGENT);
        // word-occupancy mask: ballot bit l = (row l>>4, word l&15) nonzero
        const unsigned long long wb = __ballot(v != 0ull);
        if ((tid & 15) == 0)
            __hip_atomic_store(&wm_g[j], (unsigned int)((wb >> (16*rr)) & 0xFFFFull),
                               __ATOMIC_RELAXED, __HIP_MEMORY_SCOPE_AGENT);
    }
    __syncthreads();   // all waves done with phase-1 LDS before reuse
    if (tid == 0) {
        asm volatile("s_waitcnt vmcnt(0)" ::: "memory");   // wave-0 data stores done
        __hip_atomic_store(&slotB[b], MB_MAGIC, __ATOMIC_RELAXED, __HIP_MEMORY_SCOPE_AGENT);
    }

    if (b == 0) {
        // ---- phase 2: clustering (proven R4 algorithm), pipelined staging ----
        unsigned long long* mat = (unsigned long long*)smem;                 // 128 KB
        unsigned short* wm = (unsigned short*)(smem + 131072);               // 2 KB
        unsigned long long* seed_lds = (unsigned long long*)(smem + 133120); // 16 u64
        int* rankb = (int*)(smem + 133248);                                  // 16 int
        unsigned long long* packL = (unsigned long long*)(smem + 133312);    // 2 KB

        if (tid < NW) { seed_lds[tid] = 0ull; rankb[tid] = 0; }

        // thread t waits for publisher block t, then stages its 4 rows
        while (__hip_atomic_load(&slotB[tid], __ATOMIC_RELAXED, __HIP_MEMORY_SCOPE_AGENT) != MB_MAGIC)
            __builtin_amdgcn_s_sleep(1);
        #pragma unroll
        for (int rr = 0; rr < 4; ++rr) {
            const int r = tid * 4 + rr;
            const unsigned int m16 =
                __hip_atomic_load(&wm_g[r], __ATOMIC_RELAXED, __HIP_MEMORY_SCOPE_AGENT) & 0xFFFFu;
            wm[r] = (unsigned short)m16;
            unsigned int t16 = m16;
            while (t16) {
                const int w = __ffs(t16) - 1;
                t16 &= t16 - 1;
                mat[widx(r, w)] =
                    __hip_atomic_load(&maskT[(size_t)r * NW + w],
                                      __ATOMIC_RELAXED, __HIP_MEMORY_SCOPE_AGENT);
            }
        }
        __syncthreads();

        // phase B: wave 0, 16 sequential chunks (exact ref greedy semantics)
        if (tid < 64) {
            int base = 0;
            for (int c = 0; c < NW; ++c) {
                const int row = c * 64 + tid;
                unsigned int f = (unsigned int)wm[row];
                unsigned long long acc = 0ull, Dt = 0ull;
                while (f) {
                    const int w = __ffs(f) - 1;
                    f &= f - 1;
                    const unsigned long long v = mat[widx(row, w)];
                    acc |= v & seed_lds[w];          // seeds of future chunks are 0
                    if (w == c) Dt = v;              // in-edges within my chunk
                }
                const bool elig = (acc == 0ull);
                const unsigned long long E = __ballot(elig);
                const unsigned long long inlow = Dt & ((1ull << tid) - 1ull);

                // ballot fixpoint: S(j) = E(j) && no seed t<j with edge t->j
                unsigned long long S = E;
                #pragma unroll 1
                for (int it = 0; it < 64; ++it) {
                    const bool killed = (inlow & S) != 0ull;
                    const unsigned long long S2 = E & __ballot(!killed);
                    if (S2 == S) break;
                    S = S2;
                }

                if (tid == 0) { seed_lds[c] = S; rankb[c] = base; }
                base += (int)__popcll(S);
            }
        }
        __syncthreads();

        // phase C: label(j) = rank of max-index seed covering j; pack 4xu16/u64
        {
            unsigned long long pk = 0ull;
            #pragma unroll
            for (int rr = 0; rr < 4; ++rr) {
                const int r = tid * 4 + rr;
                unsigned int f = (unsigned int)wm[r];
                int best = -1;
                while (f) {
                    const int w = __ffs(f) - 1;
                    f &= f - 1;
                    const unsigned long long bits = mat[widx(r, w)] & seed_lds[w];
                    if (bits) best = (w << 6) | (63 - __clzll(bits));  // w ascending
                }
                int lbl = 0;
                if (best >= 0) {
                    const int w = best >> 6, pos = best & 63;
                    lbl = rankb[w] + (int)__popcll(seed_lds[w] & ((1ull << pos) - 1ull)) + 1;
                }
                pk |= (unsigned long long)(unsigned)lbl << (16 * rr);
            }
            packL[tid] = pk;
        }
        __syncthreads();

        // publish labels: wave 0 only, then waitcnt + flag (no fences)
        if (tid < 64) {
            #pragma unroll
            for (int q = 0; q < 4; ++q)
                __hip_atomic_store(&ci_pack[tid + q*64], packL[tid + q*64],
                                   __ATOMIC_RELAXED, __HIP_MEMORY_SCOPE_AGENT);
        }
        if (tid == 0) {
            asm volatile("s_waitcnt vmcnt(0)" ::: "memory");
            __hip_atomic_store(flagC, MC_MAGIC, __ATOMIC_RELAXED, __HIP_MEMORY_SCOPE_AGENT);
        }
    } else {
        if (tid == 0) {
            while (__hip_atomic_load(flagC, __ATOMIC_RELAXED, __HIP_MEMORY_SCOPE_AGENT) != MC_MAGIC)
                __builtin_amdgcn_s_sleep(1);
        }
    }
    __syncthreads();

    // ---- phase 3: fusion, wave w of block b handles cluster b*4+w+1 ----
    {
        float* ms = (float*)smem + wave * 1024;            // 4 KB/wave
        int*   mi = (int*)(smem + 16384) + wave * 1024;    // 4 KB/wave
        const int target = b * 4 + wave + 1;
        const int ob = target - 1;

        unsigned int mymask = 0;
        #pragma unroll
        for (int k4 = 0; k4 < 4; ++k4) {
            const unsigned long long pw =
                __hip_atomic_load(&ci_pack[lane * 4 + k4],
                                  __ATOMIC_RELAXED, __HIP_MEMORY_SCOPE_AGENT);
            #pragma unroll
            for (int s = 0; s < 4; ++s)
                if (((pw >> (16*s)) & 0xFFFFull) == (unsigned long long)(unsigned)target)
                    mymask |= 1u << (k4*4 + s);
        }
        const bool anyv = (__ballot(mymask != 0) != 0ULL);

        float* outb = out + (size_t)ob * 7;
        float* outs = out + 7 * NB;
        float* outv = out + 8 * NB;

        if (!anyv) {
            if (lane == 0) {
                #pragma unroll
                for (int c = 0; c < 7; ++c) outb[c] = 0.0f;
                outs[ob] = 0.0f;
                outv[ob] = 0.0f;
            }
        } else {
            // pass 1: ssum + argmax (first index of max)
            float ssum = 0.0f, smax = -1.0f;
            int sidx = 1 << 30;
            #pragma unroll
            for (int k = 0; k < 16; ++k) {
                if (mymask & (1u << k)) {
                    const int idx = lane * 16 + k;
                    const float s = scores[idx];
                    ssum += s;
                    if (s > smax || (s == smax && idx < sidx)) { smax = s; sidx = idx; }
                }
            }
            #pragma unroll
            for (int off = 32; off >= 1; off >>= 1) {
                ssum += __shfl_xor(ssum, off);
                const float om = __shfl_xor(smax, off);
                const int   oi = __shfl_xor(sidx, off);
                if (om > smax || (om == smax && oi < sidx)) { smax = om; sidx = oi; }
            }
            const float ref = limit_period_f(boxes[sidx * 7 + 6]);

            // pass 2: sc_gt
            float sc_gt = 0.0f;
            #pragma unroll
            for (int k = 0; k < 16; ++k) {
                if (mymask & (1u << k)) {
                    const int idx = lane * 16 + k;
                    const float dir = limit_period_f(boxes[idx * 7 + 6]);
                    float diff = fabsf(dir - ref);
                    if (diff > PI_F) diff = 2.0f * PI_F - diff;
                    if (diff > PI_F * 0.5f) sc_gt += scores[idx];
                }
            }
            #pragma unroll
            for (int off = 32; off >= 1; off >>= 1) sc_gt += __shfl_xor(sc_gt, off);
            const bool flip_gt = (sc_gt <= (ssum - sc_gt));

            // pass 3: weighted sums
            float acc[6] = {0,0,0,0,0,0};
            float ssin = 0.0f, scos = 0.0f;
            #pragma unroll
            for (int k = 0; k < 16; ++k) {
                if (mymask & (1u << k)) {
                    const int idx = lane * 16 + k;
                    const float s = scores[idx];
                    const float w = s / ssum;
                    const float dir = limit_period_f(boxes[idx * 7 + 6]);
                    float diff = fabsf(dir - ref);
                    if (diff > PI_F) diff = 2.0f * PI_F - diff;
                    const bool gt = (diff > PI_F * 0.5f);
                    const bool add = flip_gt ? gt : (!gt);
                    const float d2 = limit_period_f(dir + (add ? PI_F : 0.0f));
                    float sd, cd;
                    sincosf(d2, &sd, &cd);
                    ssin += sd * w;
                    scos += cd * w;
                    #pragma unroll
                    for (int c = 0; c < 6; ++c) acc[c] += boxes[idx * 7 + c] * w;
                }
            }
            #pragma unroll
            for (int off = 32; off >= 1; off >>= 1) {
                ssin += __shfl_xor(ssin, off);
                scos += __shfl_xor(scos, off);
                #pragma unroll
                for (int c = 0; c < 6; ++c) acc[c] += __shfl_xor(acc[c], off);
            }
            const float theta = atan2f(ssin, scos);

            // pass 4: score fusion via tie-broken ranks (== sorted-power sum)
            const int cnt = __popc(mymask);
            int x = cnt;
            #pragma unroll
            for (int off = 1; off < 64; off <<= 1) {
                const int y = __shfl_up(x, off);
                if (lane >= off) x += y;
            }
            const int base = x - cnt;
            const int K = __shfl(x, 63);
            {
                int p = base;
                #pragma unroll
                for (int k = 0; k < 16; ++k) {
                    if (mymask & (1u << k)) {
                        const int idx = lane * 16 + k;
                        ms[p] = scores[idx];
                        mi[p] = idx;
                        ++p;
                    }
                }
            }
            // per-wave buffers: no cross-wave sync needed
            float sf = 0.0f;
            for (int e = lane; e < K; e += 64) {
                const float v = ms[e];
                const int ix = mi[e];
                int rank = 0;
                for (int t = 0; t < K; ++t) {
                    const float u = ms[t];
                    if (u > v || (u == v && mi[t] < ix)) ++rank;
                }
                sf += powf(v, (float)(rank + 1));
            }
            #pragma unroll
            for (int off = 32; off >= 1; off >>= 1) sf += __shfl_xor(sf, off);
            sf = fminf(sf, 1.0f);

            if (lane == 0) {
                #pragma unroll
                for (int c = 0; c < 6; ++c) outb[c] = acc[c];
                outb[6] = theta;
                outs[ob] = sf;
                outv[ob] = 1.0f;
            }
        }
    }
}

// ---------------------------------------------------------------------------
extern "C" void kernel_launch(void* const* d_in, const int* in_sizes, int n_in,
                              void* d_out, int out_size, void* d_ws, size_t ws_size,
                              hipStream_t stream) {
    const float* boxes  = (const float*)d_in[0];   // (1024,7) f32
    const float* scores = (const float*)d_in[1];   // (1024,)  f32
    float* out = (float*)d_out;

    char* ws = (char*)d_ws;
    unsigned long long* maskT = (unsigned long long*)ws;            // 128 KB @ 0
    unsigned int* wm_g = (unsigned int*)(ws + 131072);              // 4 KB
    unsigned long long* ci_pack = (unsigned long long*)(ws + 135168); // 2 KB
    unsigned int* slotB = (unsigned int*)(ws + 137216);             // 1 KB
    unsigned int* flagC = (unsigned int*)(ws + 138240);             // 4 B

    const size_t SMEM = 135360;  // max(phase1 ~49K, cluster 128K+2K+... +packL 2K)
    (void)hipFuncSetAttribute((const void*)fused_kernel,
                              hipFuncAttributeMaxDynamicSharedMemorySize, (int)SMEM);
    fused_kernel<<<NBLK, 256, SMEM, stream>>>(
        boxes, scores, out, maskT, wm_g, ci_pack, slotB, flagC);
}